// Round 13
// baseline (242.528 us; speedup 1.0000x reference)
//
#include <hip/hip_runtime.h>
#include <hip/hip_bf16.h>

// Problem constants
#define B_    8
#define NA_   4096
#define NAA_  1024
#define NPC_  4096
#define K_    16
#define KNC_  14
#define G_    32
#define DA_   12
#define F_    128
#define D_    128

typedef __attribute__((ext_vector_type(8))) short short8;
typedef __attribute__((ext_vector_type(4))) float floatx4;

__device__ __forceinline__ unsigned short f2bf(float x) {
    __hip_bfloat16 h = __float2bfloat16(x);
    return *reinterpret_cast<unsigned short*>(&h);
}
__device__ __forceinline__ float bf2f(unsigned short u) {
    __hip_bfloat16 h;
    *reinterpret_cast<unsigned short*>(&h) = u;
    return __bfloat162float(h);
}
__device__ __forceinline__ float bflo(unsigned int u) {   // low bf16 of pair
    return __uint_as_float(u << 16);
}
__device__ __forceinline__ float bfhi(unsigned int u) {   // high bf16 of pair
    return __uint_as_float(u & 0xffff0000u);
}

// ---------------------------------------------------------------------------
// k_prep: transpose weights to bf16 + zero stats (block 320).
//   WnT[f][ga] = W_nem[ga][f]          (128 x 384)
//   W2T[n][k]  = n<128 ? W_att[k][n] : W_feat[k][n-128]   (256 x 128)
// ---------------------------------------------------------------------------
__global__ __launch_bounds__(256) void k_prep(
    const float* __restrict__ W_nem, const float* __restrict__ W_att,
    const float* __restrict__ W_feat,
    unsigned short* __restrict__ WnT, unsigned short* __restrict__ W2T,
    float* __restrict__ stats)   // 257 floats: S1[128],S2[128],n
{
    if (blockIdx.x == 320) {
        if (threadIdx.x < 257) stats[threadIdx.x] = 0.f;
        return;
    }
    const int idx = blockIdx.x * 256 + threadIdx.x;   // < 81920
    if (idx < 128 * 384) {
        const int f = idx / 384, ga = idx % 384;
        WnT[idx] = f2bf(W_nem[(size_t)ga * F_ + f]);
    } else if (idx < 128 * 384 + 256 * 128) {
        const int j = idx - 128 * 384;
        const int n = j / 128, k = j % 128;
        const float v = (n < 128) ? W_att[(size_t)k * F_ + n]
                                  : W_feat[(size_t)k * F_ + (n - 128)];
        W2T[j] = f2bf(v);
    }
}

// ---------------------------------------------------------------------------
// k_fused: geometry -> M (LDS) -> Y (LDS) -> AF2 (global), 16 atoms/block.
// 2048 blocks, 8 blocks/CU (LDS ~17.8 KB, launch_bounds(256,8)) — halves the
// per-block gather critical path vs the 32-atom variant and doubles resident
// waves for latency overlap. Phase C keeps the broadcast-friendly t=idx>>5
// mapping (0 bank conflicts). AF2[atom][f] = uint32(att bf16 | feat bf16<<16).
// ---------------------------------------------------------------------------
__global__ __launch_bounds__(256, 8) void k_fused(
    const float* __restrict__ pc,         // (B,NPC,3)
    const float* __restrict__ mask_atom,  // (B,NA)
    const float* __restrict__ attr_table, // (39,12)
    const float* __restrict__ gauss,      // (32,3)
    const int* __restrict__ frame_idx,    // (B,NA,3)
    const int* __restrict__ attr_idx,     // (B,NA)
    const int* __restrict__ nb_idx,       // (B,NA,16)
    const unsigned short* __restrict__ WnT,   // (128,384)
    const unsigned short* __restrict__ W2T,   // (256,128)
    float* __restrict__ mask_y,
    unsigned int* __restrict__ AF2)           // (32768,128) packed
{
    const int a0  = blockIdx.x * 16;      // first atom
    const int b   = a0 >> 12;             // NA = 4096
    const int tid = threadIdx.x;
    const int wave = tid >> 6, lane = tid & 63;
    const int l15 = lane & 15, quad = lane >> 4;

    __shared__ __align__(16) char u_region[16 * 392 * 2]; // Ms | geo alias (12544 B)
    __shared__ unsigned short Ys[16][136];                // 4352 B
    __shared__ float Rs[16][9];
    __shared__ float cen[16][3];
    __shared__ float mk[16];

    unsigned short (*Ms)[392]    = (unsigned short(*)[392])u_region;
    float4        (*rel4)[K_]    = (float4(*)[K_])u_region;                   // 4096 B
    unsigned int  (*anbP)[K_][6] = (unsigned int(*)[K_][6])(u_region + 4096); // 6144 B

    // ---- phase A: frames + masks (threads 0..15) ----
    if (tid < 16) {
        const int atom = a0 + tid;
        const int fb = atom * 3;
        const int i0 = frame_idx[fb + 0];
        const int i1 = frame_idx[fb + 1];
        const int i2 = frame_idx[fb + 2];
        const float* pcb = pc + (size_t)b * NPC_ * 3;
        float p0x = pcb[i0*3+0], p0y = pcb[i0*3+1], p0z = pcb[i0*3+2];
        float cx  = pcb[i1*3+0], cy  = pcb[i1*3+1], cz  = pcb[i1*3+2];
        float p2x = pcb[i2*3+0], p2y = pcb[i2*3+1], p2z = pcb[i2*3+2];
        float u1x = p2x - cx, u1y = p2y - cy, u1z = p2z - cz;
        float n1 = sqrtf(u1x*u1x + u1y*u1y + u1z*u1z) + 1e-8f;
        u1x /= n1; u1y /= n1; u1z /= n1;
        float vx = p0x - cx, vy = p0y - cy, vz = p0z - cz;
        float dot = vx*u1x + vy*u1y + vz*u1z;
        float u2x = vx - dot*u1x, u2y = vy - dot*u1y, u2z = vz - dot*u1z;
        float n2 = sqrtf(u2x*u2x + u2y*u2y + u2z*u2z) + 1e-8f;
        u2x /= n2; u2y /= n2; u2z /= n2;
        float u3x = u1y*u2z - u1z*u2y;
        float u3y = u1z*u2x - u1x*u2z;
        float u3z = u1x*u2y - u1y*u2x;
        Rs[tid][0]=u1x; Rs[tid][1]=u1y; Rs[tid][2]=u1z;
        Rs[tid][3]=u2x; Rs[tid][4]=u2y; Rs[tid][5]=u2z;
        Rs[tid][6]=u3x; Rs[tid][7]=u3y; Rs[tid][8]=u3z;
        cen[tid][0]=cx; cen[tid][1]=cy; cen[tid][2]=cz;
        const int ai = attr_idx[atom];
        float m = 0.f;
        #pragma unroll
        for (int a = 0; a < DA_; a++)
            if (attr_table[ai*DA_ + a] != 0.f) m = 1.f;
        const float mv = mask_atom[atom] * m;
        mk[tid] = mv;
        mask_y[atom] = mv;
    }
    __syncthreads();

    // ---- phase B: rel coords + packed neighbor attrs (256 tasks, 1 iter) ---
    {
        const int t = tid >> 4, k = tid & 15;     // t < 16
        const int j  = nb_idx[(a0 + t) * K_ + k];
        const int ai = attr_idx[b * NA_ + j];
        const int fj = frame_idx[(b * NA_ + j) * 3 + 1];
        const float* pcb = pc + (size_t)b * NPC_ * 3;
        float dx = pcb[fj*3+0] - cen[t][0];
        float dy = pcb[fj*3+1] - cen[t][1];
        float dz = pcb[fj*3+2] - cen[t][2];
        float4 r;
        r.x = Rs[t][0]*dx + Rs[t][1]*dy + Rs[t][2]*dz;
        r.y = Rs[t][3]*dx + Rs[t][4]*dy + Rs[t][5]*dz;
        r.z = Rs[t][6]*dx + Rs[t][7]*dy + Rs[t][8]*dz;
        r.w = 0.f;
        rel4[t][k] = r;
        const float4* src = (const float4*)attr_table + (size_t)ai * 3;
        #pragma unroll
        for (int q = 0; q < 3; q++) {
            const float4 v = src[q];
            anbP[t][k][q*2]   = (unsigned int)f2bf(v.x) | ((unsigned int)f2bf(v.y) << 16);
            anbP[t][k][q*2+1] = (unsigned int)f2bf(v.z) | ((unsigned int)f2bf(v.w) << 16);
        }
    }
    __syncthreads();

    // ---- phase C: contraction into REGISTERS (broadcast-friendly mapping) --
    float accR[2][DA_];
    #pragma unroll
    for (int it = 0; it < 2; it++) {
        const int idx = tid + it * 256;          // < 512
        const int t = idx >> 5, g = idx & 31;    // t < 16
        const float gx = gauss[g*3+0], gy = gauss[g*3+1], gz = gauss[g*3+2];
        float* acc = accR[it];
        #pragma unroll
        for (int a = 0; a < DA_; a++) acc[a] = 0.f;
        #pragma unroll
        for (int k = 0; k < K_; k++) {
            const float4 r = rel4[t][k];
            const float dx = r.x - gx, dy = r.y - gy, dz = r.z - gz;
            const float gv = __expf(-0.5f * (dx*dx + dy*dy + dz*dz));
            #pragma unroll
            for (int q = 0; q < 6; q++) {
                const unsigned int u = anbP[t][k][q];
                acc[2*q]   += gv * bflo(u);
                acc[2*q+1] += gv * bfhi(u);
            }
        }
    }
    __syncthreads();   // all geo reads done; Ms may now overwrite the region

    #pragma unroll
    for (int it = 0; it < 2; it++) {
        const int idx = tid + it * 256;
        const int t = idx >> 5, g = idx & 31;
        unsigned int* dst = (unsigned int*)&Ms[t][g * 12];
        const float* acc = accR[it];
        #pragma unroll
        for (int i = 0; i < 6; i++) {
            const unsigned int lo = f2bf(acc[2*i]);
            const unsigned int hi = f2bf(acc[2*i+1]);
            dst[i] = lo | (hi << 16);
        }
    }
    __syncthreads();

    // ---- stage 1: Y = (M @ WnT^T) * mask/16, into Ys (16 rows) ----
    const int n0 = wave * 32;
    const unsigned short* bp0 = WnT + (size_t)(n0 + l15) * 384 + quad * 8;
    const unsigned short* bp1 = bp0 + (size_t)16 * 384;

    floatx4 c00 = {0.f,0.f,0.f,0.f}, c01 = {0.f,0.f,0.f,0.f};
    #pragma unroll
    for (int k0 = 0; k0 < 384; k0 += 32) {
        short8 a0v = *reinterpret_cast<const short8*>(&Ms[l15][quad * 8 + k0]);
        short8 b0 = *reinterpret_cast<const short8*>(bp0 + k0);
        short8 b1 = *reinterpret_cast<const short8*>(bp1 + k0);
        c00 = __builtin_amdgcn_mfma_f32_16x16x32_bf16(a0v, b0, c00, 0, 0, 0);
        c01 = __builtin_amdgcn_mfma_f32_16x16x32_bf16(a0v, b1, c01, 0, 0, 0);
    }
    #pragma unroll
    for (int r = 0; r < 4; r++) {
        const int r0 = quad * 4 + r;
        const float s0 = mk[r0] * (1.f / 16.f);
        Ys[r0][n0 + l15]      = f2bf(c00[r] * s0);
        Ys[r0][n0 + 16 + l15] = f2bf(c01[r] * s0);
    }
    __syncthreads();

    // ---- stage 2: att cols [32w,32w+32) + feat cols [32w,32w+32) ----
    const int cw = wave * 32;

    floatx4 f0[4];
    #pragma unroll
    for (int t = 0; t < 4; t++) f0[t] = (floatx4){0.f,0.f,0.f,0.f};
    const unsigned short* bq[4];
    #pragma unroll
    for (int t = 0; t < 4; t++) {
        const int nrow = (t < 2) ? (cw + 16 * t + l15)
                                 : (128 + cw + 16 * (t - 2) + l15);
        bq[t] = W2T + (size_t)nrow * F_ + quad * 8;
    }
    #pragma unroll
    for (int k0 = 0; k0 < 128; k0 += 32) {
        short8 a0v = *reinterpret_cast<const short8*>(&Ys[l15][k0 + quad * 8]);
        #pragma unroll
        for (int t = 0; t < 4; t++) {
            short8 bv = *reinterpret_cast<const short8*>(bq[t] + k0);
            f0[t] = __builtin_amdgcn_mfma_f32_16x16x32_bf16(a0v, bv, f0[t], 0, 0, 0);
        }
    }
    #pragma unroll
    for (int r = 0; r < 4; r++) {
        const int r0 = quad * 4 + r;
        const float s0 = mk[r0];
        unsigned int* o0 = AF2 + (size_t)(a0 + r0) * F_ + cw + l15;
        #pragma unroll
        for (int tp = 0; tp < 2; tp++) {
            const unsigned int p0 = (unsigned int)f2bf(f0[tp][r] * s0)
                                  | ((unsigned int)f2bf(f0[tp + 2][r] * s0) << 16);
            o0[tp * 16] = p0;
        }
    }
}

// ---------------------------------------------------------------------------
// k_pool_stats: masked/gated softmax pooling (16 rows/block) + fused stats.
// Reads packed AF2: one dword gather per neighbor -> (att, feat).
// ---------------------------------------------------------------------------
__global__ __launch_bounds__(256) void k_pool_stats(
    const unsigned int* __restrict__ AF2,
    const float* __restrict__ mask_y,
    const float* __restrict__ mask_aa,     // (B,NAA)
    const int* __restrict__ seq_idx_atom,  // (B,NA)
    const int* __restrict__ seq_idx_aa,    // (B,NAA)
    const int* __restrict__ aa_nb_idx,     // (B,NAA,14)
    float* __restrict__ pooled,
    float* __restrict__ stats)             // S1[128],S2[128],n
{
    const int tid  = threadIdx.x;
    const int rl   = tid >> 7;             // 0..1
    const int f    = tid & 127;
    const int row0 = blockIdx.x * 16;

    __shared__ float gateS[16][KNC_], maskS[16][KNC_];
    __shared__ int   jS[16][KNC_];
    __shared__ float red[128];

    if (tid < 16 * KNC_) {
        const int r = tid / KNC_, k = tid % KNC_;
        const int rr = row0 + r;
        const int bb = rr >> 10;
        const int j = aa_nb_idx[rr * KNC_ + k];
        jS[r][k] = j;
        maskS[r][k] = mask_y[bb * NA_ + j];
        const int sa = seq_idx_aa[rr];
        const int sn = seq_idx_atom[bb * NA_ + j];
        gateS[r][k] = (sn == sa) ? 1.f : 0.f;
    }
    __syncthreads();

    float s1 = 0.f, s2 = 0.f;
    #pragma unroll
    for (int it = 0; it < 8; it++) {
        const int r   = it * 2 + rl;
        const int row = row0 + r;
        const int bb  = row >> 10;

        float av[KNC_], fv[KNC_];
        #pragma unroll
        for (int k = 0; k < KNC_; k++) {
            const unsigned int u = AF2[((size_t)(bb * NA_ + jS[r][k])) * F_ + f];
            av[k] = bflo(u);
            fv[k] = bfhi(u);
        }
        float m = -1e30f;
        #pragma unroll
        for (int k = 0; k < KNC_; k++) {
            const float l = (maskS[r][k] > 0.f) ? av[k] : -1e9f;
            av[k] = l;
            m = fmaxf(m, l);
        }
        float s = 0.f;
        #pragma unroll
        for (int k = 0; k < KNC_; k++) { av[k] = __expf(av[k] - m); s += av[k]; }
        float tot = 0.f, p = 0.f;
        #pragma unroll
        for (int k = 0; k < KNC_; k++) {
            const float w = av[k] / s * gateS[r][k] * maskS[r][k];
            tot += w;
            p   += w * fv[k];
        }
        p = p / (tot + 1e-8f);
        p *= mask_aa[row];
        pooled[(size_t)row * F_ + f] = p;
        s1 += p;
        s2 += p * p;
    }

    // block-level reduce then one atomic per feature per stat
    if (rl == 1) red[f] = s1;
    __syncthreads();
    if (rl == 0) atomicAdd(&stats[f], s1 + red[f]);
    __syncthreads();
    if (rl == 1) red[f] = s2;
    __syncthreads();
    if (rl == 0) atomicAdd(&stats[F_ + f], s2 + red[f]);
    if (tid == 0) {
        float n = 0.f;
        #pragma unroll
        for (int r = 0; r < 16; r++) n += mask_aa[row0 + r];
        atomicAdd(&stats[2 * F_], n);
    }
}

// ---------------------------------------------------------------------------
// k_final: batchnorm + relu + float4 store; echo mask_aa as output 1.
// ---------------------------------------------------------------------------
__global__ __launch_bounds__(256) void k_final(
    const float4* __restrict__ pooled4,
    const float* __restrict__ stats,
    const float* __restrict__ gamma,
    const float* __restrict__ beta,
    const float* __restrict__ mask_aa,
    float4* __restrict__ out4)
{
    const int idx = blockIdx.x * 256 + threadIdx.x;   // < 262144
    const int f0  = (idx & 31) * 4;
    const int row = idx >> 5;
    const float n = stats[2 * F_] + 1e-8f;
    const float ma = mask_aa[row];
    const float4 p = pooled4[idx];
    float4 v;
    {
        const float mean = stats[f0+0] / n;
        const float var  = stats[F_ + f0+0] / n - mean * mean;
        v.x = fmaxf((gamma[f0+0] * (p.x - mean) * rsqrtf(var + 1e-5f) + beta[f0+0]) * ma, 0.f);
    }
    {
        const float mean = stats[f0+1] / n;
        const float var  = stats[F_ + f0+1] / n - mean * mean;
        v.y = fmaxf((gamma[f0+1] * (p.y - mean) * rsqrtf(var + 1e-5f) + beta[f0+1]) * ma, 0.f);
    }
    {
        const float mean = stats[f0+2] / n;
        const float var  = stats[F_ + f0+2] / n - mean * mean;
        v.z = fmaxf((gamma[f0+2] * (p.z - mean) * rsqrtf(var + 1e-5f) + beta[f0+2]) * ma, 0.f);
    }
    {
        const float mean = stats[f0+3] / n;
        const float var  = stats[F_ + f0+3] / n - mean * mean;
        v.w = fmaxf((gamma[f0+3] * (p.w - mean) * rsqrtf(var + 1e-5f) + beta[f0+3]) * ma, 0.f);
    }
    out4[idx] = v;
    if (idx < (B_ * NAA_) / 4)
        out4[(B_ * NAA_ * D_) / 4 + idx] = ((const float4*)mask_aa)[idx];
}

// ---------------------------------------------------------------------------
extern "C" void kernel_launch(void* const* d_in, const int* in_sizes, int n_in,
                              void* d_out, int out_size, void* d_ws, size_t ws_size,
                              hipStream_t stream) {
    const float* pc         = (const float*)d_in[0];
    const float* mask_atom  = (const float*)d_in[1];
    const float* mask_aa    = (const float*)d_in[2];
    const float* attr_table = (const float*)d_in[3];
    const float* gauss      = (const float*)d_in[4];
    const float* W_nem      = (const float*)d_in[5];
    const float* W_att      = (const float*)d_in[6];
    const float* W_feat     = (const float*)d_in[7];
    const float* gamma      = (const float*)d_in[8];
    const float* beta       = (const float*)d_in[9];
    const int* frame_idx    = (const int*)d_in[10];
    const int* attr_idx     = (const int*)d_in[11];
    const int* nb_idx       = (const int*)d_in[12];
    const int* seq_idx_atom = (const int*)d_in[13];
    const int* seq_idx_aa   = (const int*)d_in[14];
    const int* aa_nb_idx    = (const int*)d_in[15];

    // Workspace layout (~21.3 MB of the provided ws)
    char* base = (char*)d_ws;
    unsigned int*   AF2 = (unsigned int*)base;                           // 16777216
    unsigned short* WnT = (unsigned short*)(base + 16777216);            // 98304
    unsigned short* W2T = (unsigned short*)(base + 16777216 + 98304);    // 65536
    float* masky  = (float*)(base + 16777216 + 98304 + 65536);           // 131072
    float* pooled = (float*)(base + 16777216 + 98304 + 65536 + 131072);  // 4194304
    float* stats  = (float*)(base + 16777216 + 98304 + 65536 + 131072 + 4194304);

    k_prep<<<321, 256, 0, stream>>>(W_nem, W_att, W_feat, WnT, W2T, stats);
    k_fused<<<B_*NA_/16, 256, 0, stream>>>(pc, mask_atom, attr_table, gauss,
                                           frame_idx, attr_idx, nb_idx,
                                           WnT, W2T, masky, AF2);
    k_pool_stats<<<B_*NAA_/16, 256, 0, stream>>>(AF2, masky, mask_aa,
                                                 seq_idx_atom, seq_idx_aa,
                                                 aa_nb_idx, pooled, stats);
    k_final<<<(B_*NAA_*D_/4) / 256, 256, 0, stream>>>((const float4*)pooled,
                                                      stats, gamma, beta,
                                                      mask_aa, (float4*)d_out);
}

// Round 14
// 170.371 us; speedup vs baseline: 1.4235x; 1.4235x over previous
//
#include <hip/hip_runtime.h>
#include <hip/hip_bf16.h>

// Problem constants
#define B_    8
#define NA_   4096
#define NAA_  1024
#define NPC_  4096
#define K_    16
#define KNC_  14
#define G_    32
#define DA_   12
#define F_    128
#define D_    128

typedef __attribute__((ext_vector_type(8))) short short8;
typedef __attribute__((ext_vector_type(4))) float floatx4;

__device__ __forceinline__ unsigned short f2bf(float x) {
    __hip_bfloat16 h = __float2bfloat16(x);
    return *reinterpret_cast<unsigned short*>(&h);
}
__device__ __forceinline__ float bf2f(unsigned short u) {
    __hip_bfloat16 h;
    *reinterpret_cast<unsigned short*>(&h) = u;
    return __bfloat162float(h);
}
__device__ __forceinline__ float bflo(unsigned int u) {   // low bf16 of pair
    return __uint_as_float(u << 16);
}
__device__ __forceinline__ float bfhi(unsigned int u) {   // high bf16 of pair
    return __uint_as_float(u & 0xffff0000u);
}

// ---------------------------------------------------------------------------
// k_prep: transpose weights to bf16 + zero stats (block 320).
//   WnT[f][ga] = W_nem[ga][f]          (128 x 384)
//   W2T[n][k]  = n<128 ? W_att[k][n] : W_feat[k][n-128]   (256 x 128)
// ---------------------------------------------------------------------------
__global__ __launch_bounds__(256) void k_prep(
    const float* __restrict__ W_nem, const float* __restrict__ W_att,
    const float* __restrict__ W_feat,
    unsigned short* __restrict__ WnT, unsigned short* __restrict__ W2T,
    float* __restrict__ stats)   // 257 floats: S1[128],S2[128],n
{
    if (blockIdx.x == 320) {
        if (threadIdx.x < 257) stats[threadIdx.x] = 0.f;
        return;
    }
    const int idx = blockIdx.x * 256 + threadIdx.x;   // < 81920
    if (idx < 128 * 384) {
        const int f = idx / 384, ga = idx % 384;
        WnT[idx] = f2bf(W_nem[(size_t)ga * F_ + f]);
    } else if (idx < 128 * 384 + 256 * 128) {
        const int j = idx - 128 * 384;
        const int n = j / 128, k = j % 128;
        const float v = (n < 128) ? W_att[(size_t)k * F_ + n]
                                  : W_feat[(size_t)k * F_ + (n - 128)];
        W2T[j] = f2bf(v);
    }
}

// ---------------------------------------------------------------------------
// k_fused: geometry -> M (LDS) -> Y (LDS) -> AF2 (global), 16 atoms/block.
// 2048 blocks. launch_bounds(256,4): 128-VGPR cap — R13's (256,8) forced a
// 32-VGPR cap and spilled ~350 MB to scratch (FETCH 128MB/WRITE 266MB, 242µs).
// Actual VGPR ~64 + LDS 17.9 KB lets HW co-schedule up to 8 blocks/CU anyway.
// AF2[atom][f] = uint32(att bf16 | feat bf16 << 16).
// ---------------------------------------------------------------------------
__global__ __launch_bounds__(256, 4) void k_fused(
    const float* __restrict__ pc,         // (B,NPC,3)
    const float* __restrict__ mask_atom,  // (B,NA)
    const float* __restrict__ attr_table, // (39,12)
    const float* __restrict__ gauss,      // (32,3)
    const int* __restrict__ frame_idx,    // (B,NA,3)
    const int* __restrict__ attr_idx,     // (B,NA)
    const int* __restrict__ nb_idx,       // (B,NA,16)
    const unsigned short* __restrict__ WnT,   // (128,384)
    const unsigned short* __restrict__ W2T,   // (256,128)
    float* __restrict__ mask_y,
    unsigned int* __restrict__ AF2)           // (32768,128) packed
{
    const int a0  = blockIdx.x * 16;      // first atom
    const int b   = a0 >> 12;             // NA = 4096
    const int tid = threadIdx.x;
    const int wave = tid >> 6, lane = tid & 63;
    const int l15 = lane & 15, quad = lane >> 4;

    __shared__ __align__(16) char u_region[16 * 392 * 2]; // Ms | geo alias (12544 B)
    __shared__ unsigned short Ys[16][136];                // 4352 B
    __shared__ float Rs[16][9];
    __shared__ float cen[16][3];
    __shared__ float mk[16];

    unsigned short (*Ms)[392]    = (unsigned short(*)[392])u_region;
    float4        (*rel4)[K_]    = (float4(*)[K_])u_region;                   // 4096 B
    unsigned int  (*anbP)[K_][6] = (unsigned int(*)[K_][6])(u_region + 4096); // 6144 B

    // ---- phase A: frames + masks (threads 0..15) ----
    if (tid < 16) {
        const int atom = a0 + tid;
        const int fb = atom * 3;
        const int i0 = frame_idx[fb + 0];
        const int i1 = frame_idx[fb + 1];
        const int i2 = frame_idx[fb + 2];
        const float* pcb = pc + (size_t)b * NPC_ * 3;
        float p0x = pcb[i0*3+0], p0y = pcb[i0*3+1], p0z = pcb[i0*3+2];
        float cx  = pcb[i1*3+0], cy  = pcb[i1*3+1], cz  = pcb[i1*3+2];
        float p2x = pcb[i2*3+0], p2y = pcb[i2*3+1], p2z = pcb[i2*3+2];
        float u1x = p2x - cx, u1y = p2y - cy, u1z = p2z - cz;
        float n1 = sqrtf(u1x*u1x + u1y*u1y + u1z*u1z) + 1e-8f;
        u1x /= n1; u1y /= n1; u1z /= n1;
        float vx = p0x - cx, vy = p0y - cy, vz = p0z - cz;
        float dot = vx*u1x + vy*u1y + vz*u1z;
        float u2x = vx - dot*u1x, u2y = vy - dot*u1y, u2z = vz - dot*u1z;
        float n2 = sqrtf(u2x*u2x + u2y*u2y + u2z*u2z) + 1e-8f;
        u2x /= n2; u2y /= n2; u2z /= n2;
        float u3x = u1y*u2z - u1z*u2y;
        float u3y = u1z*u2x - u1x*u2z;
        float u3z = u1x*u2y - u1y*u2x;
        Rs[tid][0]=u1x; Rs[tid][1]=u1y; Rs[tid][2]=u1z;
        Rs[tid][3]=u2x; Rs[tid][4]=u2y; Rs[tid][5]=u2z;
        Rs[tid][6]=u3x; Rs[tid][7]=u3y; Rs[tid][8]=u3z;
        cen[tid][0]=cx; cen[tid][1]=cy; cen[tid][2]=cz;
        const int ai = attr_idx[atom];
        float m = 0.f;
        #pragma unroll
        for (int a = 0; a < DA_; a++)
            if (attr_table[ai*DA_ + a] != 0.f) m = 1.f;
        const float mv = mask_atom[atom] * m;
        mk[tid] = mv;
        mask_y[atom] = mv;
    }
    __syncthreads();

    // ---- phase B: rel coords + packed neighbor attrs (256 tasks, 1 iter) ---
    {
        const int t = tid >> 4, k = tid & 15;     // t < 16
        const int j  = nb_idx[(a0 + t) * K_ + k];
        const int ai = attr_idx[b * NA_ + j];
        const int fj = frame_idx[(b * NA_ + j) * 3 + 1];
        const float* pcb = pc + (size_t)b * NPC_ * 3;
        float dx = pcb[fj*3+0] - cen[t][0];
        float dy = pcb[fj*3+1] - cen[t][1];
        float dz = pcb[fj*3+2] - cen[t][2];
        float4 r;
        r.x = Rs[t][0]*dx + Rs[t][1]*dy + Rs[t][2]*dz;
        r.y = Rs[t][3]*dx + Rs[t][4]*dy + Rs[t][5]*dz;
        r.z = Rs[t][6]*dx + Rs[t][7]*dy + Rs[t][8]*dz;
        r.w = 0.f;
        rel4[t][k] = r;
        const float4* src = (const float4*)attr_table + (size_t)ai * 3;
        #pragma unroll
        for (int q = 0; q < 3; q++) {
            const float4 v = src[q];
            anbP[t][k][q*2]   = (unsigned int)f2bf(v.x) | ((unsigned int)f2bf(v.y) << 16);
            anbP[t][k][q*2+1] = (unsigned int)f2bf(v.z) | ((unsigned int)f2bf(v.w) << 16);
        }
    }
    __syncthreads();

    // ---- phase C: contraction into REGISTERS (broadcast-friendly mapping) --
    float accR[2][DA_];
    #pragma unroll
    for (int it = 0; it < 2; it++) {
        const int idx = tid + it * 256;          // < 512
        const int t = idx >> 5, g = idx & 31;    // t < 16
        const float gx = gauss[g*3+0], gy = gauss[g*3+1], gz = gauss[g*3+2];
        float* acc = accR[it];
        #pragma unroll
        for (int a = 0; a < DA_; a++) acc[a] = 0.f;
        #pragma unroll
        for (int k = 0; k < K_; k++) {
            const float4 r = rel4[t][k];
            const float dx = r.x - gx, dy = r.y - gy, dz = r.z - gz;
            const float gv = __expf(-0.5f * (dx*dx + dy*dy + dz*dz));
            #pragma unroll
            for (int q = 0; q < 6; q++) {
                const unsigned int u = anbP[t][k][q];
                acc[2*q]   += gv * bflo(u);
                acc[2*q+1] += gv * bfhi(u);
            }
        }
    }
    __syncthreads();   // all geo reads done; Ms may now overwrite the region

    #pragma unroll
    for (int it = 0; it < 2; it++) {
        const int idx = tid + it * 256;
        const int t = idx >> 5, g = idx & 31;
        unsigned int* dst = (unsigned int*)&Ms[t][g * 12];
        const float* acc = accR[it];
        #pragma unroll
        for (int i = 0; i < 6; i++) {
            const unsigned int lo = f2bf(acc[2*i]);
            const unsigned int hi = f2bf(acc[2*i+1]);
            dst[i] = lo | (hi << 16);
        }
    }
    __syncthreads();

    // ---- stage 1: Y = (M @ WnT^T) * mask/16, into Ys (16 rows) ----
    const int n0 = wave * 32;
    const unsigned short* bp0 = WnT + (size_t)(n0 + l15) * 384 + quad * 8;
    const unsigned short* bp1 = bp0 + (size_t)16 * 384;

    floatx4 c00 = {0.f,0.f,0.f,0.f}, c01 = {0.f,0.f,0.f,0.f};
    #pragma unroll
    for (int k0 = 0; k0 < 384; k0 += 32) {
        short8 a0v = *reinterpret_cast<const short8*>(&Ms[l15][quad * 8 + k0]);
        short8 b0 = *reinterpret_cast<const short8*>(bp0 + k0);
        short8 b1 = *reinterpret_cast<const short8*>(bp1 + k0);
        c00 = __builtin_amdgcn_mfma_f32_16x16x32_bf16(a0v, b0, c00, 0, 0, 0);
        c01 = __builtin_amdgcn_mfma_f32_16x16x32_bf16(a0v, b1, c01, 0, 0, 0);
    }
    #pragma unroll
    for (int r = 0; r < 4; r++) {
        const int r0 = quad * 4 + r;
        const float s0 = mk[r0] * (1.f / 16.f);
        Ys[r0][n0 + l15]      = f2bf(c00[r] * s0);
        Ys[r0][n0 + 16 + l15] = f2bf(c01[r] * s0);
    }
    __syncthreads();

    // ---- stage 2: att cols [32w,32w+32) + feat cols [32w,32w+32) ----
    const int cw = wave * 32;

    floatx4 f0[4];
    #pragma unroll
    for (int t = 0; t < 4; t++) f0[t] = (floatx4){0.f,0.f,0.f,0.f};
    const unsigned short* bq[4];
    #pragma unroll
    for (int t = 0; t < 4; t++) {
        const int nrow = (t < 2) ? (cw + 16 * t + l15)
                                 : (128 + cw + 16 * (t - 2) + l15);
        bq[t] = W2T + (size_t)nrow * F_ + quad * 8;
    }
    #pragma unroll
    for (int k0 = 0; k0 < 128; k0 += 32) {
        short8 a0v = *reinterpret_cast<const short8*>(&Ys[l15][k0 + quad * 8]);
        #pragma unroll
        for (int t = 0; t < 4; t++) {
            short8 bv = *reinterpret_cast<const short8*>(bq[t] + k0);
            f0[t] = __builtin_amdgcn_mfma_f32_16x16x32_bf16(a0v, bv, f0[t], 0, 0, 0);
        }
    }
    #pragma unroll
    for (int r = 0; r < 4; r++) {
        const int r0 = quad * 4 + r;
        const float s0 = mk[r0];
        unsigned int* o0 = AF2 + (size_t)(a0 + r0) * F_ + cw + l15;
        #pragma unroll
        for (int tp = 0; tp < 2; tp++) {
            const unsigned int p0 = (unsigned int)f2bf(f0[tp][r] * s0)
                                  | ((unsigned int)f2bf(f0[tp + 2][r] * s0) << 16);
            o0[tp * 16] = p0;
        }
    }
}

// ---------------------------------------------------------------------------
// k_pool_stats: masked/gated softmax pooling (16 rows/block) + fused stats.
// Reads packed AF2: one dword gather per neighbor -> (att, feat).
// ---------------------------------------------------------------------------
__global__ __launch_bounds__(256) void k_pool_stats(
    const unsigned int* __restrict__ AF2,
    const float* __restrict__ mask_y,
    const float* __restrict__ mask_aa,     // (B,NAA)
    const int* __restrict__ seq_idx_atom,  // (B,NA)
    const int* __restrict__ seq_idx_aa,    // (B,NAA)
    const int* __restrict__ aa_nb_idx,     // (B,NAA,14)
    float* __restrict__ pooled,
    float* __restrict__ stats)             // S1[128],S2[128],n
{
    const int tid  = threadIdx.x;
    const int rl   = tid >> 7;             // 0..1
    const int f    = tid & 127;
    const int row0 = blockIdx.x * 16;

    __shared__ float gateS[16][KNC_], maskS[16][KNC_];
    __shared__ int   jS[16][KNC_];
    __shared__ float red[128];

    if (tid < 16 * KNC_) {
        const int r = tid / KNC_, k = tid % KNC_;
        const int rr = row0 + r;
        const int bb = rr >> 10;
        const int j = aa_nb_idx[rr * KNC_ + k];
        jS[r][k] = j;
        maskS[r][k] = mask_y[bb * NA_ + j];
        const int sa = seq_idx_aa[rr];
        const int sn = seq_idx_atom[bb * NA_ + j];
        gateS[r][k] = (sn == sa) ? 1.f : 0.f;
    }
    __syncthreads();

    float s1 = 0.f, s2 = 0.f;
    #pragma unroll
    for (int it = 0; it < 8; it++) {
        const int r   = it * 2 + rl;
        const int row = row0 + r;
        const int bb  = row >> 10;

        float av[KNC_], fv[KNC_];
        #pragma unroll
        for (int k = 0; k < KNC_; k++) {
            const unsigned int u = AF2[((size_t)(bb * NA_ + jS[r][k])) * F_ + f];
            av[k] = bflo(u);
            fv[k] = bfhi(u);
        }
        float m = -1e30f;
        #pragma unroll
        for (int k = 0; k < KNC_; k++) {
            const float l = (maskS[r][k] > 0.f) ? av[k] : -1e9f;
            av[k] = l;
            m = fmaxf(m, l);
        }
        float s = 0.f;
        #pragma unroll
        for (int k = 0; k < KNC_; k++) { av[k] = __expf(av[k] - m); s += av[k]; }
        float tot = 0.f, p = 0.f;
        #pragma unroll
        for (int k = 0; k < KNC_; k++) {
            const float w = av[k] / s * gateS[r][k] * maskS[r][k];
            tot += w;
            p   += w * fv[k];
        }
        p = p / (tot + 1e-8f);
        p *= mask_aa[row];
        pooled[(size_t)row * F_ + f] = p;
        s1 += p;
        s2 += p * p;
    }

    // block-level reduce then one atomic per feature per stat
    if (rl == 1) red[f] = s1;
    __syncthreads();
    if (rl == 0) atomicAdd(&stats[f], s1 + red[f]);
    __syncthreads();
    if (rl == 1) red[f] = s2;
    __syncthreads();
    if (rl == 0) atomicAdd(&stats[F_ + f], s2 + red[f]);
    if (tid == 0) {
        float n = 0.f;
        #pragma unroll
        for (int r = 0; r < 16; r++) n += mask_aa[row0 + r];
        atomicAdd(&stats[2 * F_], n);
    }
}

// ---------------------------------------------------------------------------
// k_final: batchnorm + relu + float4 store; echo mask_aa as output 1.
// ---------------------------------------------------------------------------
__global__ __launch_bounds__(256) void k_final(
    const float4* __restrict__ pooled4,
    const float* __restrict__ stats,
    const float* __restrict__ gamma,
    const float* __restrict__ beta,
    const float* __restrict__ mask_aa,
    float4* __restrict__ out4)
{
    const int idx = blockIdx.x * 256 + threadIdx.x;   // < 262144
    const int f0  = (idx & 31) * 4;
    const int row = idx >> 5;
    const float n = stats[2 * F_] + 1e-8f;
    const float ma = mask_aa[row];
    const float4 p = pooled4[idx];
    float4 v;
    {
        const float mean = stats[f0+0] / n;
        const float var  = stats[F_ + f0+0] / n - mean * mean;
        v.x = fmaxf((gamma[f0+0] * (p.x - mean) * rsqrtf(var + 1e-5f) + beta[f0+0]) * ma, 0.f);
    }
    {
        const float mean = stats[f0+1] / n;
        const float var  = stats[F_ + f0+1] / n - mean * mean;
        v.y = fmaxf((gamma[f0+1] * (p.y - mean) * rsqrtf(var + 1e-5f) + beta[f0+1]) * ma, 0.f);
    }
    {
        const float mean = stats[f0+2] / n;
        const float var  = stats[F_ + f0+2] / n - mean * mean;
        v.z = fmaxf((gamma[f0+2] * (p.z - mean) * rsqrtf(var + 1e-5f) + beta[f0+2]) * ma, 0.f);
    }
    {
        const float mean = stats[f0+3] / n;
        const float var  = stats[F_ + f0+3] / n - mean * mean;
        v.w = fmaxf((gamma[f0+3] * (p.w - mean) * rsqrtf(var + 1e-5f) + beta[f0+3]) * ma, 0.f);
    }
    out4[idx] = v;
    if (idx < (B_ * NAA_) / 4)
        out4[(B_ * NAA_ * D_) / 4 + idx] = ((const float4*)mask_aa)[idx];
}

// ---------------------------------------------------------------------------
extern "C" void kernel_launch(void* const* d_in, const int* in_sizes, int n_in,
                              void* d_out, int out_size, void* d_ws, size_t ws_size,
                              hipStream_t stream) {
    const float* pc         = (const float*)d_in[0];
    const float* mask_atom  = (const float*)d_in[1];
    const float* mask_aa    = (const float*)d_in[2];
    const float* attr_table = (const float*)d_in[3];
    const float* gauss      = (const float*)d_in[4];
    const float* W_nem      = (const float*)d_in[5];
    const float* W_att      = (const float*)d_in[6];
    const float* W_feat     = (const float*)d_in[7];
    const float* gamma      = (const float*)d_in[8];
    const float* beta       = (const float*)d_in[9];
    const int* frame_idx    = (const int*)d_in[10];
    const int* attr_idx     = (const int*)d_in[11];
    const int* nb_idx       = (const int*)d_in[12];
    const int* seq_idx_atom = (const int*)d_in[13];
    const int* seq_idx_aa   = (const int*)d_in[14];
    const int* aa_nb_idx    = (const int*)d_in[15];

    // Workspace layout (~21.3 MB of the provided ws)
    char* base = (char*)d_ws;
    unsigned int*   AF2 = (unsigned int*)base;                           // 16777216
    unsigned short* WnT = (unsigned short*)(base + 16777216);            // 98304
    unsigned short* W2T = (unsigned short*)(base + 16777216 + 98304);    // 65536
    float* masky  = (float*)(base + 16777216 + 98304 + 65536);           // 131072
    float* pooled = (float*)(base + 16777216 + 98304 + 65536 + 131072);  // 4194304
    float* stats  = (float*)(base + 16777216 + 98304 + 65536 + 131072 + 4194304);

    k_prep<<<321, 256, 0, stream>>>(W_nem, W_att, W_feat, WnT, W2T, stats);
    k_fused<<<B_*NA_/16, 256, 0, stream>>>(pc, mask_atom, attr_table, gauss,
                                           frame_idx, attr_idx, nb_idx,
                                           WnT, W2T, masky, AF2);
    k_pool_stats<<<B_*NAA_/16, 256, 0, stream>>>(AF2, masky, mask_aa,
                                                 seq_idx_atom, seq_idx_aa,
                                                 aa_nb_idx, pooled, stats);
    k_final<<<(B_*NAA_*D_/4) / 256, 256, 0, stream>>>((const float4*)pooled,
                                                      stats, gamma, beta,
                                                      mask_aa, (float4*)d_out);
}

// Round 15
// 149.255 us; speedup vs baseline: 1.6249x; 1.1415x over previous
//
#include <hip/hip_runtime.h>
#include <hip/hip_bf16.h>

// Problem constants
#define B_    8
#define NA_   4096
#define NAA_  1024
#define NPC_  4096
#define K_    16
#define KNC_  14
#define G_    32
#define DA_   12
#define F_    128
#define D_    128

typedef __attribute__((ext_vector_type(8))) short short8;
typedef __attribute__((ext_vector_type(4))) float floatx4;

__device__ __forceinline__ unsigned short f2bf(float x) {
    __hip_bfloat16 h = __float2bfloat16(x);
    return *reinterpret_cast<unsigned short*>(&h);
}
__device__ __forceinline__ float bf2f(unsigned short u) {
    __hip_bfloat16 h;
    *reinterpret_cast<unsigned short*>(&h) = u;
    return __bfloat162float(h);
}
__device__ __forceinline__ float bflo(unsigned int u) {   // low bf16 of pair
    return __uint_as_float(u << 16);
}
__device__ __forceinline__ float bfhi(unsigned int u) {   // high bf16 of pair
    return __uint_as_float(u & 0xffff0000u);
}

// ---------------------------------------------------------------------------
// k_prep: transpose weights to bf16 + zero stats (block 320).
//   WnT[f][ga] = W_nem[ga][f]          (128 x 384)
//   W2T[n][k]  = n<128 ? W_att[k][n] : W_feat[k][n-128]   (256 x 128)
// ---------------------------------------------------------------------------
__global__ __launch_bounds__(256) void k_prep(
    const float* __restrict__ W_nem, const float* __restrict__ W_att,
    const float* __restrict__ W_feat,
    unsigned short* __restrict__ WnT, unsigned short* __restrict__ W2T,
    float* __restrict__ stats)   // 257 floats: S1[128],S2[128],n
{
    if (blockIdx.x == 320) {
        if (threadIdx.x < 257) stats[threadIdx.x] = 0.f;
        return;
    }
    const int idx = blockIdx.x * 256 + threadIdx.x;   // < 81920
    if (idx < 128 * 384) {
        const int f = idx / 384, ga = idx % 384;
        WnT[idx] = f2bf(W_nem[(size_t)ga * F_ + f]);
    } else if (idx < 128 * 384 + 256 * 128) {
        const int j = idx - 128 * 384;
        const int n = j / 128, k = j % 128;
        const float v = (n < 128) ? W_att[(size_t)k * F_ + n]
                                  : W_feat[(size_t)k * F_ + (n - 128)];
        W2T[j] = f2bf(v);
    }
}

// ---------------------------------------------------------------------------
// k_fused: geometry -> M (LDS) -> Y (LDS) -> AF2 (global), 32 atoms/block.
// R12-verified best config (149.9 µs total). 16-atom split (R13/R14) regressed:
// (256,8) forced 32-VGPR spills (+350MB scratch); at (256,4) it doubled
// per-MFMA B-traffic with no occupancy gain (37.5% either way).
// Phase C: t=idx>>5 broadcast mapping, 0 bank conflicts (t=tid>>3 hit 8-way).
// AF2[atom][f] = uint32( att bf16 | feat bf16 << 16 ).
// ---------------------------------------------------------------------------
__global__ __launch_bounds__(256, 4) void k_fused(
    const float* __restrict__ pc,         // (B,NPC,3)
    const float* __restrict__ mask_atom,  // (B,NA)
    const float* __restrict__ attr_table, // (39,12)
    const float* __restrict__ gauss,      // (32,3)
    const int* __restrict__ frame_idx,    // (B,NA,3)
    const int* __restrict__ attr_idx,     // (B,NA)
    const int* __restrict__ nb_idx,       // (B,NA,16)
    const unsigned short* __restrict__ WnT,   // (128,384)
    const unsigned short* __restrict__ W2T,   // (256,128)
    float* __restrict__ mask_y,
    unsigned int* __restrict__ AF2)           // (32768,128) packed
{
    const int a0  = blockIdx.x * 32;      // first atom
    const int b   = a0 >> 12;             // NA = 4096
    const int tid = threadIdx.x;
    const int wave = tid >> 6, lane = tid & 63;
    const int l15 = lane & 15, quad = lane >> 4;

    __shared__ __align__(16) char u_region[32 * 392 * 2]; // Ms | geo alias
    __shared__ unsigned short Ys[32][136];                // 8704 B
    __shared__ float Rs[32][9];
    __shared__ float cen[32][3];
    __shared__ float mk[32];

    unsigned short (*Ms)[392]    = (unsigned short(*)[392])u_region;
    float4        (*rel4)[K_]    = (float4(*)[K_])u_region;                   // 8192 B
    unsigned int  (*anbP)[K_][6] = (unsigned int(*)[K_][6])(u_region + 8192); // 12288 B

    // ---- phase A: frames + masks (threads 0..31) ----
    if (tid < 32) {
        const int atom = a0 + tid;
        const int fb = atom * 3;
        const int i0 = frame_idx[fb + 0];
        const int i1 = frame_idx[fb + 1];
        const int i2 = frame_idx[fb + 2];
        const float* pcb = pc + (size_t)b * NPC_ * 3;
        float p0x = pcb[i0*3+0], p0y = pcb[i0*3+1], p0z = pcb[i0*3+2];
        float cx  = pcb[i1*3+0], cy  = pcb[i1*3+1], cz  = pcb[i1*3+2];
        float p2x = pcb[i2*3+0], p2y = pcb[i2*3+1], p2z = pcb[i2*3+2];
        float u1x = p2x - cx, u1y = p2y - cy, u1z = p2z - cz;
        float n1 = sqrtf(u1x*u1x + u1y*u1y + u1z*u1z) + 1e-8f;
        u1x /= n1; u1y /= n1; u1z /= n1;
        float vx = p0x - cx, vy = p0y - cy, vz = p0z - cz;
        float dot = vx*u1x + vy*u1y + vz*u1z;
        float u2x = vx - dot*u1x, u2y = vy - dot*u1y, u2z = vz - dot*u1z;
        float n2 = sqrtf(u2x*u2x + u2y*u2y + u2z*u2z) + 1e-8f;
        u2x /= n2; u2y /= n2; u2z /= n2;
        float u3x = u1y*u2z - u1z*u2y;
        float u3y = u1z*u2x - u1x*u2z;
        float u3z = u1x*u2y - u1y*u2x;
        Rs[tid][0]=u1x; Rs[tid][1]=u1y; Rs[tid][2]=u1z;
        Rs[tid][3]=u2x; Rs[tid][4]=u2y; Rs[tid][5]=u2z;
        Rs[tid][6]=u3x; Rs[tid][7]=u3y; Rs[tid][8]=u3z;
        cen[tid][0]=cx; cen[tid][1]=cy; cen[tid][2]=cz;
        const int ai = attr_idx[atom];
        float m = 0.f;
        #pragma unroll
        for (int a = 0; a < DA_; a++)
            if (attr_table[ai*DA_ + a] != 0.f) m = 1.f;
        const float mv = mask_atom[atom] * m;
        mk[tid] = mv;
        mask_y[atom] = mv;
    }
    __syncthreads();

    // ---- phase B: rel coords + packed neighbor attrs (512 tasks, 2 iters) --
    #pragma unroll
    for (int it = 0; it < 2; it++) {
        const int idx = tid + it * 256;          // < 512
        const int t = idx >> 4, k = idx & 15;
        const int j  = nb_idx[(a0 + t) * K_ + k];
        const int ai = attr_idx[b * NA_ + j];
        const int fj = frame_idx[(b * NA_ + j) * 3 + 1];
        const float* pcb = pc + (size_t)b * NPC_ * 3;
        float dx = pcb[fj*3+0] - cen[t][0];
        float dy = pcb[fj*3+1] - cen[t][1];
        float dz = pcb[fj*3+2] - cen[t][2];
        float4 r;
        r.x = Rs[t][0]*dx + Rs[t][1]*dy + Rs[t][2]*dz;
        r.y = Rs[t][3]*dx + Rs[t][4]*dy + Rs[t][5]*dz;
        r.z = Rs[t][6]*dx + Rs[t][7]*dy + Rs[t][8]*dz;
        r.w = 0.f;
        rel4[t][k] = r;
        const float4* src = (const float4*)attr_table + (size_t)ai * 3;
        #pragma unroll
        for (int q = 0; q < 3; q++) {
            const float4 v = src[q];
            anbP[t][k][q*2]   = (unsigned int)f2bf(v.x) | ((unsigned int)f2bf(v.y) << 16);
            anbP[t][k][q*2+1] = (unsigned int)f2bf(v.z) | ((unsigned int)f2bf(v.w) << 16);
        }
    }
    __syncthreads();

    // ---- phase C: contraction into REGISTERS (broadcast-friendly mapping) --
    float accR[4][DA_];
    #pragma unroll
    for (int it = 0; it < 4; it++) {
        const int idx = tid + it * 256;          // < 1024
        const int t = idx >> 5, g = idx & 31;
        const float gx = gauss[g*3+0], gy = gauss[g*3+1], gz = gauss[g*3+2];
        float* acc = accR[it];
        #pragma unroll
        for (int a = 0; a < DA_; a++) acc[a] = 0.f;
        #pragma unroll
        for (int k = 0; k < K_; k++) {
            const float4 r = rel4[t][k];
            const float dx = r.x - gx, dy = r.y - gy, dz = r.z - gz;
            const float gv = __expf(-0.5f * (dx*dx + dy*dy + dz*dz));
            #pragma unroll
            for (int q = 0; q < 6; q++) {
                const unsigned int u = anbP[t][k][q];
                acc[2*q]   += gv * bflo(u);
                acc[2*q+1] += gv * bfhi(u);
            }
        }
    }
    __syncthreads();   // all geo reads done; Ms may now overwrite the region

    #pragma unroll
    for (int it = 0; it < 4; it++) {
        const int idx = tid + it * 256;
        const int t = idx >> 5, g = idx & 31;
        unsigned int* dst = (unsigned int*)&Ms[t][g * 12];
        const float* acc = accR[it];
        #pragma unroll
        for (int i = 0; i < 6; i++) {
            const unsigned int lo = f2bf(acc[2*i]);
            const unsigned int hi = f2bf(acc[2*i+1]);
            dst[i] = lo | (hi << 16);
        }
    }
    __syncthreads();

    // ---- stage 1: Y = (M @ WnT^T) * mask/16, into Ys ----
    const int n0 = wave * 32;
    const unsigned short* bp0 = WnT + (size_t)(n0 + l15) * 384 + quad * 8;
    const unsigned short* bp1 = bp0 + (size_t)16 * 384;

    floatx4 c00 = {0.f,0.f,0.f,0.f}, c01 = {0.f,0.f,0.f,0.f};
    floatx4 c10 = {0.f,0.f,0.f,0.f}, c11 = {0.f,0.f,0.f,0.f};
    #pragma unroll
    for (int k0 = 0; k0 < 384; k0 += 32) {
        short8 a0v = *reinterpret_cast<const short8*>(&Ms[l15][quad * 8 + k0]);
        short8 a1v = *reinterpret_cast<const short8*>(&Ms[16 + l15][quad * 8 + k0]);
        short8 b0 = *reinterpret_cast<const short8*>(bp0 + k0);
        short8 b1 = *reinterpret_cast<const short8*>(bp1 + k0);
        c00 = __builtin_amdgcn_mfma_f32_16x16x32_bf16(a0v, b0, c00, 0, 0, 0);
        c01 = __builtin_amdgcn_mfma_f32_16x16x32_bf16(a0v, b1, c01, 0, 0, 0);
        c10 = __builtin_amdgcn_mfma_f32_16x16x32_bf16(a1v, b0, c10, 0, 0, 0);
        c11 = __builtin_amdgcn_mfma_f32_16x16x32_bf16(a1v, b1, c11, 0, 0, 0);
    }
    #pragma unroll
    for (int r = 0; r < 4; r++) {
        const int r0 = quad * 4 + r;
        const float s0 = mk[r0]      * (1.f / 16.f);
        const float s1 = mk[16 + r0] * (1.f / 16.f);
        Ys[r0][n0 + l15]           = f2bf(c00[r] * s0);
        Ys[r0][n0 + 16 + l15]      = f2bf(c01[r] * s0);
        Ys[16 + r0][n0 + l15]      = f2bf(c10[r] * s1);
        Ys[16 + r0][n0 + 16 + l15] = f2bf(c11[r] * s1);
    }
    __syncthreads();

    // ---- stage 2: att cols [32w,32w+32) + feat cols [32w,32w+32) ----
    const int cw = wave * 32;

    floatx4 f0[4], f1[4];
    #pragma unroll
    for (int t = 0; t < 4; t++) {
        f0[t] = (floatx4){0.f,0.f,0.f,0.f};
        f1[t] = (floatx4){0.f,0.f,0.f,0.f};
    }
    const unsigned short* bq[4];
    #pragma unroll
    for (int t = 0; t < 4; t++) {
        const int nrow = (t < 2) ? (cw + 16 * t + l15)
                                 : (128 + cw + 16 * (t - 2) + l15);
        bq[t] = W2T + (size_t)nrow * F_ + quad * 8;
    }
    #pragma unroll
    for (int k0 = 0; k0 < 128; k0 += 32) {
        short8 a0v = *reinterpret_cast<const short8*>(&Ys[l15][k0 + quad * 8]);
        short8 a1v = *reinterpret_cast<const short8*>(&Ys[16 + l15][k0 + quad * 8]);
        #pragma unroll
        for (int t = 0; t < 4; t++) {
            short8 bv = *reinterpret_cast<const short8*>(bq[t] + k0);
            f0[t] = __builtin_amdgcn_mfma_f32_16x16x32_bf16(a0v, bv, f0[t], 0, 0, 0);
            f1[t] = __builtin_amdgcn_mfma_f32_16x16x32_bf16(a1v, bv, f1[t], 0, 0, 0);
        }
    }
    #pragma unroll
    for (int r = 0; r < 4; r++) {
        const int r0 = quad * 4 + r;
        const float s0 = mk[r0], s1 = mk[16 + r0];
        unsigned int* o0 = AF2 + (size_t)(a0 + r0) * F_ + cw + l15;
        unsigned int* o1 = AF2 + (size_t)(a0 + 16 + r0) * F_ + cw + l15;
        #pragma unroll
        for (int tp = 0; tp < 2; tp++) {
            const unsigned int p0 = (unsigned int)f2bf(f0[tp][r] * s0)
                                  | ((unsigned int)f2bf(f0[tp + 2][r] * s0) << 16);
            const unsigned int p1 = (unsigned int)f2bf(f1[tp][r] * s1)
                                  | ((unsigned int)f2bf(f1[tp + 2][r] * s1) << 16);
            o0[tp * 16] = p0;
            o1[tp * 16] = p1;
        }
    }
}

// ---------------------------------------------------------------------------
// k_pool_stats: masked/gated softmax pooling (16 rows/block) + fused stats.
// Reads packed AF2: one dword gather per neighbor -> (att, feat).
// ---------------------------------------------------------------------------
__global__ __launch_bounds__(256) void k_pool_stats(
    const unsigned int* __restrict__ AF2,
    const float* __restrict__ mask_y,
    const float* __restrict__ mask_aa,     // (B,NAA)
    const int* __restrict__ seq_idx_atom,  // (B,NA)
    const int* __restrict__ seq_idx_aa,    // (B,NAA)
    const int* __restrict__ aa_nb_idx,     // (B,NAA,14)
    float* __restrict__ pooled,
    float* __restrict__ stats)             // S1[128],S2[128],n
{
    const int tid  = threadIdx.x;
    const int rl   = tid >> 7;             // 0..1
    const int f    = tid & 127;
    const int row0 = blockIdx.x * 16;

    __shared__ float gateS[16][KNC_], maskS[16][KNC_];
    __shared__ int   jS[16][KNC_];
    __shared__ float red[128];

    if (tid < 16 * KNC_) {
        const int r = tid / KNC_, k = tid % KNC_;
        const int rr = row0 + r;
        const int bb = rr >> 10;
        const int j = aa_nb_idx[rr * KNC_ + k];
        jS[r][k] = j;
        maskS[r][k] = mask_y[bb * NA_ + j];
        const int sa = seq_idx_aa[rr];
        const int sn = seq_idx_atom[bb * NA_ + j];
        gateS[r][k] = (sn == sa) ? 1.f : 0.f;
    }
    __syncthreads();

    float s1 = 0.f, s2 = 0.f;
    #pragma unroll
    for (int it = 0; it < 8; it++) {
        const int r   = it * 2 + rl;
        const int row = row0 + r;
        const int bb  = row >> 10;

        float av[KNC_], fv[KNC_];
        #pragma unroll
        for (int k = 0; k < KNC_; k++) {
            const unsigned int u = AF2[((size_t)(bb * NA_ + jS[r][k])) * F_ + f];
            av[k] = bflo(u);
            fv[k] = bfhi(u);
        }
        float m = -1e30f;
        #pragma unroll
        for (int k = 0; k < KNC_; k++) {
            const float l = (maskS[r][k] > 0.f) ? av[k] : -1e9f;
            av[k] = l;
            m = fmaxf(m, l);
        }
        float s = 0.f;
        #pragma unroll
        for (int k = 0; k < KNC_; k++) { av[k] = __expf(av[k] - m); s += av[k]; }
        float tot = 0.f, p = 0.f;
        #pragma unroll
        for (int k = 0; k < KNC_; k++) {
            const float w = av[k] / s * gateS[r][k] * maskS[r][k];
            tot += w;
            p   += w * fv[k];
        }
        p = p / (tot + 1e-8f);
        p *= mask_aa[row];
        pooled[(size_t)row * F_ + f] = p;
        s1 += p;
        s2 += p * p;
    }

    // block-level reduce then one atomic per feature per stat
    if (rl == 1) red[f] = s1;
    __syncthreads();
    if (rl == 0) atomicAdd(&stats[f], s1 + red[f]);
    __syncthreads();
    if (rl == 1) red[f] = s2;
    __syncthreads();
    if (rl == 0) atomicAdd(&stats[F_ + f], s2 + red[f]);
    if (tid == 0) {
        float n = 0.f;
        #pragma unroll
        for (int r = 0; r < 16; r++) n += mask_aa[row0 + r];
        atomicAdd(&stats[2 * F_], n);
    }
}

// ---------------------------------------------------------------------------
// k_final: batchnorm + relu + float4 store; echo mask_aa as output 1.
// ---------------------------------------------------------------------------
__global__ __launch_bounds__(256) void k_final(
    const float4* __restrict__ pooled4,
    const float* __restrict__ stats,
    const float* __restrict__ gamma,
    const float* __restrict__ beta,
    const float* __restrict__ mask_aa,
    float4* __restrict__ out4)
{
    const int idx = blockIdx.x * 256 + threadIdx.x;   // < 262144
    const int f0  = (idx & 31) * 4;
    const int row = idx >> 5;
    const float n = stats[2 * F_] + 1e-8f;
    const float ma = mask_aa[row];
    const float4 p = pooled4[idx];
    float4 v;
    {
        const float mean = stats[f0+0] / n;
        const float var  = stats[F_ + f0+0] / n - mean * mean;
        v.x = fmaxf((gamma[f0+0] * (p.x - mean) * rsqrtf(var + 1e-5f) + beta[f0+0]) * ma, 0.f);
    }
    {
        const float mean = stats[f0+1] / n;
        const float var  = stats[F_ + f0+1] / n - mean * mean;
        v.y = fmaxf((gamma[f0+1] * (p.y - mean) * rsqrtf(var + 1e-5f) + beta[f0+1]) * ma, 0.f);
    }
    {
        const float mean = stats[f0+2] / n;
        const float var  = stats[F_ + f0+2] / n - mean * mean;
        v.z = fmaxf((gamma[f0+2] * (p.z - mean) * rsqrtf(var + 1e-5f) + beta[f0+2]) * ma, 0.f);
    }
    {
        const float mean = stats[f0+3] / n;
        const float var  = stats[F_ + f0+3] / n - mean * mean;
        v.w = fmaxf((gamma[f0+3] * (p.w - mean) * rsqrtf(var + 1e-5f) + beta[f0+3]) * ma, 0.f);
    }
    out4[idx] = v;
    if (idx < (B_ * NAA_) / 4)
        out4[(B_ * NAA_ * D_) / 4 + idx] = ((const float4*)mask_aa)[idx];
}

// ---------------------------------------------------------------------------
extern "C" void kernel_launch(void* const* d_in, const int* in_sizes, int n_in,
                              void* d_out, int out_size, void* d_ws, size_t ws_size,
                              hipStream_t stream) {
    const float* pc         = (const float*)d_in[0];
    const float* mask_atom  = (const float*)d_in[1];
    const float* mask_aa    = (const float*)d_in[2];
    const float* attr_table = (const float*)d_in[3];
    const float* gauss      = (const float*)d_in[4];
    const float* W_nem      = (const float*)d_in[5];
    const float* W_att      = (const float*)d_in[6];
    const float* W_feat     = (const float*)d_in[7];
    const float* gamma      = (const float*)d_in[8];
    const float* beta       = (const float*)d_in[9];
    const int* frame_idx    = (const int*)d_in[10];
    const int* attr_idx     = (const int*)d_in[11];
    const int* nb_idx       = (const int*)d_in[12];
    const int* seq_idx_atom = (const int*)d_in[13];
    const int* seq_idx_aa   = (const int*)d_in[14];
    const int* aa_nb_idx    = (const int*)d_in[15];

    // Workspace layout (~21.3 MB of the provided ws)
    char* base = (char*)d_ws;
    unsigned int*   AF2 = (unsigned int*)base;                           // 16777216
    unsigned short* WnT = (unsigned short*)(base + 16777216);            // 98304
    unsigned short* W2T = (unsigned short*)(base + 16777216 + 98304);    // 65536
    float* masky  = (float*)(base + 16777216 + 98304 + 65536);           // 131072
    float* pooled = (float*)(base + 16777216 + 98304 + 65536 + 131072);  // 4194304
    float* stats  = (float*)(base + 16777216 + 98304 + 65536 + 131072 + 4194304);

    k_prep<<<321, 256, 0, stream>>>(W_nem, W_att, W_feat, WnT, W2T, stats);
    k_fused<<<B_*NA_/32, 256, 0, stream>>>(pc, mask_atom, attr_table, gauss,
                                           frame_idx, attr_idx, nb_idx,
                                           WnT, W2T, masky, AF2);
    k_pool_stats<<<B_*NAA_/16, 256, 0, stream>>>(AF2, masky, mask_aa,
                                                 seq_idx_atom, seq_idx_aa,
                                                 aa_nb_idx, pooled, stats);
    k_final<<<(B_*NAA_*D_/4) / 256, 256, 0, stream>>>((const float4*)pooled,
                                                      stats, gamma, beta,
                                                      mask_aa, (float4*)d_out);
}